// Round 2
// baseline (943.514 us; speedup 1.0000x reference)
//
#include <hip/hip_runtime.h>

#define NN   4096
#define KNBR 8
#define DF   240

// ---------------------------------------------------------------------------
// Kernel A: fuse weights.
//   WA = sA * (W2 @ L0)   (32x64)   ws[0..2048)
//   WB = sB * (W1 @ L1)   (64x32)   ws[2048..4096)
//   WC = sC * (W4 @ L1)   (16x32)   ws[4096..4608)
//   WD = sD * (W3 @ L2)   (32x16)   ws[4608..5120)
// ---------------------------------------------------------------------------
__global__ __launch_bounds__(256) void fuse_w(
    const float* __restrict__ W1, const float* __restrict__ W2,
    const float* __restrict__ W3, const float* __restrict__ W4,
    const float* __restrict__ L0, const float* __restrict__ L1,
    const float* __restrict__ L2, float* __restrict__ Wf) {
  const float sA = 0.012757759076995719f;  // sqrt(1/96)/8
  const float sB = 0.019764235376052370f;  // 1/sqrt(80*32)
  const float sC = 0.034232659844072875f;  // sqrt(3)/sqrt(80*32)
  const float sD = 0.098821176880261850f;  // sqrt(5/32)/4
  int idx = blockIdx.x * 256 + threadIdx.x;
  if (idx < 2048) {                       // WA: (32x64) = W2(32x64) @ L0(64x64)
    int u = idx >> 6, c = idx & 63;
    float a = 0.f;
#pragma unroll 8
    for (int m = 0; m < 64; m++) a += W2[u * 64 + m] * L0[m * 64 + c];
    Wf[idx] = sA * a;
  } else if (idx < 4096) {                // WB: (64x32) = W1(64x32) @ L1(32x32)
    int t = idx - 2048;
    int u = t >> 5, c = t & 31;
    float a = 0.f;
#pragma unroll 8
    for (int m = 0; m < 32; m++) a += W1[u * 32 + m] * L1[m * 32 + c];
    Wf[idx] = sB * a;
  } else if (idx < 4608) {                // WC: (16x32) = W4(16x32) @ L1(32x32)
    int t = idx - 4096;
    int u = t >> 5, c = t & 31;
    float a = 0.f;
#pragma unroll 8
    for (int m = 0; m < 32; m++) a += W4[u * 32 + m] * L1[m * 32 + c];
    Wf[idx] = sC * a;
  } else if (idx < 5120) {                // WD: (32x16) = W3(32x16) @ L2(16x16)
    int t = idx - 4608;
    int u = t >> 4, c = t & 15;
    float a = 0.f;
#pragma unroll 8
    for (int m = 0; m < 16; m++) a += W3[u * 16 + m] * L2[m * 16 + c];
    Wf[idx] = sD * a;
  }
}

// ---------------------------------------------------------------------------
// Kernel B: exact kNN (k=8), per-batch. Matches reference:
//   d2 = sum((c_i - c_j)^2), diagonal excluded, stable top-k (strict <).
// grid = B * (NN/64) blocks of 64 threads; each thread = one query node.
// ---------------------------------------------------------------------------
__global__ __launch_bounds__(64) void knn_kernel(
    const float* __restrict__ coords, int* __restrict__ nbr) {
  __shared__ float sx[NN], sy[NN], sz[NN];
  const int b = blockIdx.x >> 6;        // 64 blocks per batch
  const int chunk = blockIdx.x & 63;
  const float* cb = coords + (size_t)b * NN * 3;
  for (int t = threadIdx.x; t < NN; t += 64) {
    sx[t] = cb[t * 3 + 0];
    sy[t] = cb[t * 3 + 1];
    sz[t] = cb[t * 3 + 2];
  }
  __syncthreads();
  const int i = chunk * 64 + threadIdx.x;
  const float qx = sx[i], qy = sy[i], qz = sz[i];
  float bd[KNBR];
  int bi[KNBR];
#pragma unroll
  for (int k = 0; k < KNBR; k++) { bd[k] = 3.0e38f; bi[k] = 0; }
  for (int j = 0; j < NN; j++) {
    float dx = sx[j] - qx, dy = sy[j] - qy, dz = sz[j] - qz;
    float d2 = dx * dx + dy * dy + dz * dz;
    if (j != i && d2 < bd[KNBR - 1]) {
      float vd = d2;
      int vi = j;
#pragma unroll
      for (int k = 0; k < KNBR; k++) {
        if (vd < bd[k]) {
          float td = bd[k]; int ti = bi[k];
          bd[k] = vd; bi[k] = vi;
          vd = td; vi = ti;
        }
      }
    }
  }
  int* nr = nbr + (size_t)(b * NN + i) * KNBR;
#pragma unroll
  for (int k = 0; k < KNBR; k++) nr[k] = b * NN + bi[k];
}

// ---------------------------------------------------------------------------
// Kernel C: gather neighbors, accumulate pre-weight moments, apply fused
// weights, write output. One wave (64 lanes) per node; 4 nodes per block.
//
// Moments per node (432 floats in LDS):
//   S1[32]    @ 0    : sum_e x1[u,:].ev
//   Z0[64][3] @ 32   : sum_e x0[u]*ev[k]
//   P [32][5] @ 224  : sum_e sum_i x1[u,i]*F[i][k]
//   Q [16][3] @ 384  : sum_e sum_a x2[u,a]*F[k][a]   (E2 = F^T)
// F(ev) 3x5, 11 nonzeros, S=1/sqrt(10), T=1/sqrt(30):
//   col0: (S*Y, S*X, 0)  col1: (S*Z, 0, S*X)  col2: (0, S*Z, S*Y)
//   col3: (S*X, -S*Y, 0) col4: (-T*X, -T*Y, 2T*Z)
// ---------------------------------------------------------------------------
__global__ __launch_bounds__(256) void msg_kernel(
    const float* __restrict__ feats, const float* __restrict__ coords,
    const int* __restrict__ nbr, const float* __restrict__ Wf,
    float* __restrict__ out) {
  __shared__ float fbuf[4][KNBR * DF];   // 4 x 1920 floats
  __shared__ float accb[4][432];
  __shared__ float sev[4][KNBR][3];
  __shared__ int snb[4][KNBR];

  const int w = threadIdx.x >> 6;   // wave within block -> node slot
  const int u = threadIdx.x & 63;   // lane
  const int node = blockIdx.x * 4 + w;

  if (u < KNBR) {
    int j = nbr[(size_t)node * KNBR + u];
    snb[w][u] = j;
    sev[w][u][0] = coords[j * 3 + 0] - coords[node * 3 + 0];
    sev[w][u][1] = coords[j * 3 + 1] - coords[node * 3 + 1];
    sev[w][u][2] = coords[j * 3 + 2] - coords[node * 3 + 2];
  }
  __syncthreads();

  // stage 8 neighbor feature rows (240 floats each) via float4
  {
    float4* fb4 = (float4*)fbuf[w];
    const float4* gf4 = (const float4*)feats;
#pragma unroll
    for (int it = 0; it < 8; it++) {
      int idx = u + it * 64;
      if (idx < KNBR * (DF / 4)) {
        int e = idx / 60;
        int r = idx - e * 60;
        fb4[idx] = gf4[(size_t)snb[w][e] * 60 + r];
      }
    }
  }
  __syncthreads();

  const float S_ = 0.31622776601683794f;  // 1/sqrt(10)
  const float T_ = 0.18257418583505536f;  // 1/sqrt(30)

  float z0x = 0.f, z0y = 0.f, z0z = 0.f;
  float s1 = 0.f, p0 = 0.f, p1 = 0.f, p2 = 0.f, p3 = 0.f, p4 = 0.f;
  float q0 = 0.f, q1 = 0.f, q2 = 0.f;
  const float* fw = fbuf[w];

#pragma unroll
  for (int e = 0; e < KNBR; e++) {
    float X = sev[w][e][0], Y = sev[w][e][1], Z = sev[w][e][2];
    float sxv = S_ * X, syv = S_ * Y, szv = S_ * Z;
    float txv = T_ * X, tyv = T_ * Y, t2z = 2.f * T_ * Z;
    const float* fr = fw + e * DF;
    float x0v = fr[u];
    z0x += x0v * X;
    z0y += x0v * Y;
    z0z += x0v * Z;
    if (u < 32) {
      float a0 = fr[64 + 3 * u], a1 = fr[65 + 3 * u], a2 = fr[66 + 3 * u];
      s1 += a0 * X + a1 * Y + a2 * Z;
      p0 += a0 * syv + a1 * sxv;
      p1 += a0 * szv + a2 * sxv;
      p2 += a1 * szv + a2 * syv;
      p3 += a0 * sxv - a1 * syv;
      p4 += a2 * t2z - a0 * txv - a1 * tyv;
      if (u < 16) {
        float b0 = fr[160 + 5 * u], b1 = fr[161 + 5 * u], b2 = fr[162 + 5 * u];
        float b3 = fr[163 + 5 * u], b4 = fr[164 + 5 * u];
        q0 += b0 * syv + b1 * szv + b3 * sxv - b4 * txv;
        q1 += b0 * sxv + b2 * szv - b3 * syv - b4 * tyv;
        q2 += b1 * sxv + b2 * syv + b4 * t2z;
      }
    }
  }

  float* A = accb[w];
  A[32 + 3 * u + 0] = z0x;
  A[32 + 3 * u + 1] = z0y;
  A[32 + 3 * u + 2] = z0z;
  if (u < 32) {
    A[u] = s1;
    float* pp = A + 224 + 5 * u;
    pp[0] = p0; pp[1] = p1; pp[2] = p2; pp[3] = p3; pp[4] = p4;
  }
  if (u < 16) {
    float* qq = A + 384 + 3 * u;
    qq[0] = q0; qq[1] = q1; qq[2] = q2;
  }
  __syncthreads();

  const float* WA = Wf;          // 32x64
  const float* WB = Wf + 2048;   // 64x32
  const float* WC = Wf + 4096;   // 16x32
  const float* WD = Wf + 4608;   // 32x16
  float* orow = out + (size_t)node * DF;

  // y0[u] = sum_m S1[m] * WA[m][u]
  {
    float a = 0.f;
#pragma unroll
    for (int m = 0; m < 32; m++) a += A[m] * WA[m * 64 + u];
    orow[u] = a;
  }
  // y1 flat [w1*3+k], 96 outputs (two passes over 64 lanes)
#pragma unroll
  for (int m0 = 0; m0 < 96; m0 += 64) {
    int m = m0 + u;
    if (m < 96) {
      int w1 = m / 3, k = m - w1 * 3;
      float a = 0.f;
#pragma unroll
      for (int t = 0; t < 64; t++) a += A[32 + 3 * t + k] * WB[t * 32 + w1];
#pragma unroll
      for (int t = 0; t < 16; t++) a += A[384 + 3 * t + k] * WC[t * 32 + w1];
      orow[64 + m] = a;
    }
  }
  // y2 flat [w2*5+k], 80 outputs (two passes over 64 lanes — BUGFIX: the
  // previous version did a single pass and never wrote outputs 224..239)
#pragma unroll
  for (int m0 = 0; m0 < 80; m0 += 64) {
    int m = m0 + u;
    if (m < 80) {
      int w2 = m / 5, k = m - w2 * 5;
      float a = 0.f;
#pragma unroll
      for (int t = 0; t < 32; t++) a += A[224 + 5 * t + k] * WD[t * 16 + w2];
      orow[160 + m] = a;
    }
  }
}

// ---------------------------------------------------------------------------
extern "C" void kernel_launch(void* const* d_in, const int* in_sizes, int n_in,
                              void* d_out, int out_size, void* d_ws,
                              size_t ws_size, hipStream_t stream) {
  const float* feats  = (const float*)d_in[0];
  const float* coords = (const float*)d_in[1];
  const float* W1 = (const float*)d_in[2];
  const float* W2 = (const float*)d_in[3];
  const float* W3 = (const float*)d_in[4];
  const float* W4 = (const float*)d_in[5];
  const float* L0 = (const float*)d_in[6];
  const float* L1 = (const float*)d_in[7];
  const float* L2 = (const float*)d_in[8];
  float* out = (float*)d_out;

  float* Wf = (float*)d_ws;                 // 5120 floats
  int* nbr = (int*)((float*)d_ws + 5120);   // 4*4096*8 ints

  fuse_w<<<20, 256, 0, stream>>>(W1, W2, W3, W4, L0, L1, L2, Wf);
  knn_kernel<<<256, 64, 0, stream>>>(coords, nbr);
  msg_kernel<<<4096, 256, 0, stream>>>(feats, coords, nbr, Wf, out);
}

// Round 3
// 390.256 us; speedup vs baseline: 2.4177x; 2.4177x over previous
//
#include <hip/hip_runtime.h>

#define NN   4096
#define KNBR 8
#define DF   240
#define SUBW 8    // candidate sub-ranges (waves) per kNN block
#define QPB  64   // queries per kNN block

// ---------------------------------------------------------------------------
// Kernel A: fuse weights.
//   WA = sA * (W2 @ L0)   (32x64)   ws[0..2048)
//   WB = sB * (W1 @ L1)   (64x32)   ws[2048..4096)
//   WC = sC * (W4 @ L1)   (16x32)   ws[4096..4608)
//   WD = sD * (W3 @ L2)   (32x16)   ws[4608..5120)
// ---------------------------------------------------------------------------
__global__ __launch_bounds__(256) void fuse_w(
    const float* __restrict__ W1, const float* __restrict__ W2,
    const float* __restrict__ W3, const float* __restrict__ W4,
    const float* __restrict__ L0, const float* __restrict__ L1,
    const float* __restrict__ L2, float* __restrict__ Wf) {
  const float sA = 0.012757759076995719f;  // sqrt(1/96)/8
  const float sB = 0.019764235376052370f;  // 1/sqrt(80*32)
  const float sC = 0.034232659844072875f;  // sqrt(3)/sqrt(80*32)
  const float sD = 0.098821176880261850f;  // sqrt(5/32)/4
  int idx = blockIdx.x * 256 + threadIdx.x;
  if (idx < 2048) {                       // WA: (32x64) = W2(32x64) @ L0(64x64)
    int u = idx >> 6, c = idx & 63;
    float a = 0.f;
#pragma unroll 8
    for (int m = 0; m < 64; m++) a += W2[u * 64 + m] * L0[m * 64 + c];
    Wf[idx] = sA * a;
  } else if (idx < 4096) {                // WB: (64x32) = W1(64x32) @ L1(32x32)
    int t = idx - 2048;
    int u = t >> 5, c = t & 31;
    float a = 0.f;
#pragma unroll 8
    for (int m = 0; m < 32; m++) a += W1[u * 32 + m] * L1[m * 32 + c];
    Wf[idx] = sB * a;
  } else if (idx < 4608) {                // WC: (16x32) = W4(16x32) @ L1(32x32)
    int t = idx - 4096;
    int u = t >> 5, c = t & 31;
    float a = 0.f;
#pragma unroll 8
    for (int m = 0; m < 32; m++) a += W4[u * 32 + m] * L1[m * 32 + c];
    Wf[idx] = sC * a;
  } else if (idx < 5120) {                // WD: (32x16) = W3(32x16) @ L2(16x16)
    int t = idx - 4608;
    int u = t >> 4, c = t & 15;
    float a = 0.f;
#pragma unroll 8
    for (int m = 0; m < 16; m++) a += W3[u * 16 + m] * L2[m * 16 + c];
    Wf[idx] = sD * a;
  }
}

// ---------------------------------------------------------------------------
// Kernel B: exact kNN (k=8), per-batch. Restructured for parallelism:
// block = 512 threads (8 waves) = 64 queries x 8 candidate sub-ranges.
//   lane (qi)  = query   -> candidate LDS reads are wave-broadcast (no conflict)
//   wave (sub) = candidate range [sub*512, sub*512+512)
// Private top-8 per thread -> partial lists in LDS -> wave 0 merges.
// Merge order = ascending sub = ascending candidate index; strict-< insertion
// reproduces reference top_k stable tie-break.
// grid = B * (NN/64) = 256 blocks -> 2048 waves (8 waves/CU).
// ---------------------------------------------------------------------------
__global__ __launch_bounds__(512) void knn_kernel(
    const float* __restrict__ coords, int* __restrict__ nbr) {
  __shared__ float sx[NN], sy[NN], sz[NN];         // 48 KB
  __shared__ float pd[SUBW][QPB][KNBR];            // 8 KB
  __shared__ int   pi[SUBW][QPB][KNBR];            // 8 KB
  const int b = blockIdx.x >> 6;        // 64 blocks per batch
  const int chunk = blockIdx.x & 63;
  const float* cb = coords + (size_t)b * NN * 3;
  for (int t = threadIdx.x; t < NN; t += 512) {
    sx[t] = cb[t * 3 + 0];
    sy[t] = cb[t * 3 + 1];
    sz[t] = cb[t * 3 + 2];
  }
  __syncthreads();
  const int qi  = threadIdx.x & 63;     // lane -> query within block
  const int sub = threadIdx.x >> 6;     // wave -> candidate sub-range
  const int iq  = chunk * 64 + qi;      // batch-local query id
  const float qx = sx[iq], qy = sy[iq], qz = sz[iq];
  float bd[KNBR];
  int bi[KNBR];
#pragma unroll
  for (int k = 0; k < KNBR; k++) { bd[k] = 3.0e38f; bi[k] = 0; }
  const int j0 = sub * (NN / SUBW);
  const int j1 = j0 + (NN / SUBW);
  for (int j = j0; j < j1; j++) {
    float dx = sx[j] - qx, dy = sy[j] - qy, dz = sz[j] - qz;
    float d2 = dx * dx + dy * dy + dz * dz;
    if (j != iq && d2 < bd[KNBR - 1]) {
      float vd = d2;
      int vi = j;
#pragma unroll
      for (int k = 0; k < KNBR; k++) {
        if (vd < bd[k]) {
          float td = bd[k]; int ti = bi[k];
          bd[k] = vd; bi[k] = vi;
          vd = td; vi = ti;
        }
      }
    }
  }
#pragma unroll
  for (int k = 0; k < KNBR; k++) {
    pd[sub][qi][k] = bd[k];
    pi[sub][qi][k] = bi[k];
  }
  __syncthreads();
  if (threadIdx.x < 64) {
    float md[KNBR];
    int mi[KNBR];
#pragma unroll
    for (int k = 0; k < KNBR; k++) { md[k] = 3.0e38f; mi[k] = 0; }
    for (int s = 0; s < SUBW; s++) {
      for (int k = 0; k < KNBR; k++) {
        float vd = pd[s][qi][k];
        if (!(vd < md[KNBR - 1])) break;   // partial list sorted ascending
        int vi = pi[s][qi][k];
#pragma unroll
        for (int t = 0; t < KNBR; t++) {
          if (vd < md[t]) {
            float td = md[t]; int ti = mi[t];
            md[t] = vd; mi[t] = vi;
            vd = td; vi = ti;
          }
        }
      }
    }
    int* nr = nbr + (size_t)(b * NN + iq) * KNBR;
#pragma unroll
    for (int k = 0; k < KNBR; k++) nr[k] = b * NN + mi[k];
  }
}

// ---------------------------------------------------------------------------
// Kernel C: gather neighbors, accumulate pre-weight moments, apply fused
// weights, write output. One wave (64 lanes) per node; 4 nodes per block.
//
// Moments per node (432 floats in LDS):
//   S1[32]    @ 0    : sum_e x1[u,:].ev
//   Z0[64][3] @ 32   : sum_e x0[u]*ev[k]
//   P [32][5] @ 224  : sum_e sum_i x1[u,i]*F[i][k]
//   Q [16][3] @ 384  : sum_e sum_a x2[u,a]*F[k][a]   (E2 = F^T)
// F(ev) 3x5, 11 nonzeros, S=1/sqrt(10), T=1/sqrt(30):
//   col0: (S*Y, S*X, 0)  col1: (S*Z, 0, S*X)  col2: (0, S*Z, S*Y)
//   col3: (S*X, -S*Y, 0) col4: (-T*X, -T*Y, 2T*Z)
// ---------------------------------------------------------------------------
__global__ __launch_bounds__(256) void msg_kernel(
    const float* __restrict__ feats, const float* __restrict__ coords,
    const int* __restrict__ nbr, const float* __restrict__ Wf,
    float* __restrict__ out) {
  __shared__ float fbuf[4][KNBR * DF];   // 4 x 1920 floats
  __shared__ float accb[4][432];
  __shared__ float sev[4][KNBR][3];
  __shared__ int snb[4][KNBR];

  const int w = threadIdx.x >> 6;   // wave within block -> node slot
  const int u = threadIdx.x & 63;   // lane
  const int node = blockIdx.x * 4 + w;

  if (u < KNBR) {
    int j = nbr[(size_t)node * KNBR + u];
    snb[w][u] = j;
    sev[w][u][0] = coords[j * 3 + 0] - coords[node * 3 + 0];
    sev[w][u][1] = coords[j * 3 + 1] - coords[node * 3 + 1];
    sev[w][u][2] = coords[j * 3 + 2] - coords[node * 3 + 2];
  }
  __syncthreads();

  // stage 8 neighbor feature rows (240 floats each) via float4
  {
    float4* fb4 = (float4*)fbuf[w];
    const float4* gf4 = (const float4*)feats;
#pragma unroll
    for (int it = 0; it < 8; it++) {
      int idx = u + it * 64;
      if (idx < KNBR * (DF / 4)) {
        int e = idx / 60;
        int r = idx - e * 60;
        fb4[idx] = gf4[(size_t)snb[w][e] * 60 + r];
      }
    }
  }
  __syncthreads();

  const float S_ = 0.31622776601683794f;  // 1/sqrt(10)
  const float T_ = 0.18257418583505536f;  // 1/sqrt(30)

  float z0x = 0.f, z0y = 0.f, z0z = 0.f;
  float s1 = 0.f, p0 = 0.f, p1 = 0.f, p2 = 0.f, p3 = 0.f, p4 = 0.f;
  float q0 = 0.f, q1 = 0.f, q2 = 0.f;
  const float* fw = fbuf[w];

#pragma unroll
  for (int e = 0; e < KNBR; e++) {
    float X = sev[w][e][0], Y = sev[w][e][1], Z = sev[w][e][2];
    float sxv = S_ * X, syv = S_ * Y, szv = S_ * Z;
    float txv = T_ * X, tyv = T_ * Y, t2z = 2.f * T_ * Z;
    const float* fr = fw + e * DF;
    float x0v = fr[u];
    z0x += x0v * X;
    z0y += x0v * Y;
    z0z += x0v * Z;
    if (u < 32) {
      float a0 = fr[64 + 3 * u], a1 = fr[65 + 3 * u], a2 = fr[66 + 3 * u];
      s1 += a0 * X + a1 * Y + a2 * Z;
      p0 += a0 * syv + a1 * sxv;
      p1 += a0 * szv + a2 * sxv;
      p2 += a1 * szv + a2 * syv;
      p3 += a0 * sxv - a1 * syv;
      p4 += a2 * t2z - a0 * txv - a1 * tyv;
      if (u < 16) {
        float b0 = fr[160 + 5 * u], b1 = fr[161 + 5 * u], b2 = fr[162 + 5 * u];
        float b3 = fr[163 + 5 * u], b4 = fr[164 + 5 * u];
        q0 += b0 * syv + b1 * szv + b3 * sxv - b4 * txv;
        q1 += b0 * sxv + b2 * szv - b3 * syv - b4 * tyv;
        q2 += b1 * sxv + b2 * syv + b4 * t2z;
      }
    }
  }

  float* A = accb[w];
  A[32 + 3 * u + 0] = z0x;
  A[32 + 3 * u + 1] = z0y;
  A[32 + 3 * u + 2] = z0z;
  if (u < 32) {
    A[u] = s1;
    float* pp = A + 224 + 5 * u;
    pp[0] = p0; pp[1] = p1; pp[2] = p2; pp[3] = p3; pp[4] = p4;
  }
  if (u < 16) {
    float* qq = A + 384 + 3 * u;
    qq[0] = q0; qq[1] = q1; qq[2] = q2;
  }
  __syncthreads();

  const float* WA = Wf;          // 32x64
  const float* WB = Wf + 2048;   // 64x32
  const float* WC = Wf + 4096;   // 16x32
  const float* WD = Wf + 4608;   // 32x16
  float* orow = out + (size_t)node * DF;

  // y0[u] = sum_m S1[m] * WA[m][u]
  {
    float a = 0.f;
#pragma unroll
    for (int m = 0; m < 32; m++) a += A[m] * WA[m * 64 + u];
    orow[u] = a;
  }
  // y1 flat [w1*3+k], 96 outputs (two passes over 64 lanes)
#pragma unroll
  for (int m0 = 0; m0 < 96; m0 += 64) {
    int m = m0 + u;
    if (m < 96) {
      int w1 = m / 3, k = m - w1 * 3;
      float a = 0.f;
#pragma unroll
      for (int t = 0; t < 64; t++) a += A[32 + 3 * t + k] * WB[t * 32 + w1];
#pragma unroll
      for (int t = 0; t < 16; t++) a += A[384 + 3 * t + k] * WC[t * 32 + w1];
      orow[64 + m] = a;
    }
  }
  // y2 flat [w2*5+k], 80 outputs (two passes over 64 lanes)
#pragma unroll
  for (int m0 = 0; m0 < 80; m0 += 64) {
    int m = m0 + u;
    if (m < 80) {
      int w2 = m / 5, k = m - w2 * 5;
      float a = 0.f;
#pragma unroll
      for (int t = 0; t < 32; t++) a += A[224 + 5 * t + k] * WD[t * 16 + w2];
      orow[160 + m] = a;
    }
  }
}

// ---------------------------------------------------------------------------
extern "C" void kernel_launch(void* const* d_in, const int* in_sizes, int n_in,
                              void* d_out, int out_size, void* d_ws,
                              size_t ws_size, hipStream_t stream) {
  const float* feats  = (const float*)d_in[0];
  const float* coords = (const float*)d_in[1];
  const float* W1 = (const float*)d_in[2];
  const float* W2 = (const float*)d_in[3];
  const float* W3 = (const float*)d_in[4];
  const float* W4 = (const float*)d_in[5];
  const float* L0 = (const float*)d_in[6];
  const float* L1 = (const float*)d_in[7];
  const float* L2 = (const float*)d_in[8];
  float* out = (float*)d_out;

  float* Wf = (float*)d_ws;                 // 5120 floats
  int* nbr = (int*)((float*)d_ws + 5120);   // 4*4096*8 ints

  fuse_w<<<20, 256, 0, stream>>>(W1, W2, W3, W4, L0, L1, L2, Wf);
  knn_kernel<<<256, 512, 0, stream>>>(coords, nbr);
  msg_kernel<<<4096, 256, 0, stream>>>(feats, coords, nbr, Wf, out);
}